// Round 1
// baseline (133.577 us; speedup 1.0000x reference)
//
#include <hip/hip_runtime.h>
#include <math.h>

// Disable FP contraction globally: we must replicate the reference's
// individually-rounded float32 ops (XLA CPU emits separate mul/add).
#pragma clang fp contract(off)

#define BN 65536
#define SN 4
#define HH 128
#define WW 128

struct Ray {
    float p0, p1, p2;   // cur_pos
    float d0, d1, d2;   // d_proj (ray_dir)
    int cx, cy, sx, sy;
};

// Replicates jnp.linalg.inv(proj) as computed by JAX-CPU:
// LAPACK sgetf2 (reciprocal-scale pivot column) + OpenBLAS trsm
// (unit-lower solve, then upper solve with pre-inverted diagonal
// multiplies and FMA row-updates). Exploits the fixed sparsity of the
// perspective matrix (pivot order is diagonal for these constants).
__device__ __forceinline__ void inv4(const float* P, float U[4][4]) {
#pragma clang fp contract(off)
    float a = P[10];           // P[2][2]
    float b = P[11];           // P[2][3]
    float ra = 1.0f / a;
    float l32 = P[14] * ra;    // A(3,2) * rn(1/pivot); P[14] == -1
    float t = l32 * b;
    float u33 = 0.0f - t;      // single rounding
    float rf0 = 1.0f / P[0];
    float rf1 = 1.0f / P[5];
    float ru  = 1.0f / u33;
#pragma unroll
    for (int i = 0; i < 4; i++)
#pragma unroll
        for (int j = 0; j < 4; j++) U[i][j] = 0.0f;
    U[0][0] = rf0;
    U[1][1] = rf1;
    // column 2 of inverse: rhs after L-solve = [0,0,1,-l32]
    float x3c2 = (0.0f - l32) * ru;          // recip-multiply (OpenBLAS trsm)
    float y2c2 = fmaf(0.0f - b, x3c2, 1.0f); // FMA row update
    U[2][2] = y2c2 * ra;
    U[3][2] = x3c2;
    // column 3: rhs = [0,0,0,1]
    float x3c3 = ru;
    float y2c3 = 0.0f - (b * x3c3);          // single rounding either way
    U[2][3] = y2c3 * ra;
    U[3][3] = x3c3;
}

// pos4 @ M.T with pos4 = [x,y,z,1]; sequential j=0..3, separate mul/add
// (Eigen gemm without FMA). Keep ALL terms including zeros.
__device__ __forceinline__ void xform(const float M[4][4], float x, float y, float z,
                                      float& ox, float& oy, float& oz) {
#pragma clang fp contract(off)
    float o[4];
#pragma unroll
    for (int i = 0; i < 4; i++) {
        float acc = x * M[i][0];
        acc = acc + y * M[i][1];
        acc = acc + z * M[i][2];
        acc = acc + M[i][3];   // * 1.0f exact
        o[i] = acc;
    }
    ox = o[0] / o[3];
    oy = o[1] / o[3];
    oz = o[2] / o[3];
}

__device__ __forceinline__ void march(Ray& R) {
#pragma clang fp contract(off)
    float nbx = (float)(R.cx + R.sx) / 128.0f;
    float nby = (float)(R.cy + R.sy) / 128.0f;
    float c1 = 1.0f - nby;
    float s0 = (nbx - R.p0) / R.d0;
    float s1 = (c1 - R.p1) / R.d1;
    bool ty = s0 > s1;                 // NaN compare -> false (matches numpy)
    float t = ty ? s1 : s0;
    if (s1 != s1) t = s1;              // jnp.min propagates NaN
    R.p0 = R.p0 + R.d0 * t;
    R.p1 = R.p1 + R.d1 * t;
    R.p2 = R.p2 + R.d2 * t;
    if (ty) R.cy += R.sy; else R.cx += R.sx;
}

__device__ __forceinline__ Ray make_ray(int r, const float* proj, const int* xA,
                                        const int* yA, const float* dA, const float* dsA) {
#pragma clang fp contract(off)
    float P[4][4];
#pragma unroll
    for (int i = 0; i < 16; i++) ((float*)P)[i] = proj[i];
    float U[4][4];
    inv4(proj, U);
    int xi = xA[r], yi = yA[r];
    float t0 = ((float)xi + 0.5f) / 128.0f;
    float t1 = 1.0f - ((float)yi + 0.5f) / 128.0f;
    float ux = t0 * 2.0f - 1.0f;
    float uy = t1 * 2.0f - 1.0f;
    float ds = dsA[r] * 2.0f - 1.0f;
    float vx, vy, vz;
    xform(U, ux, uy, ds, vx, vy, vz);
    float ex = vx + dA[3 * r + 0] * 0.001f;
    float ey = vy + dA[3 * r + 1] * 0.001f;
    float ez = vz + dA[3 * r + 2] * 0.001f;
    float qx, qy, qz;
    xform(P, ex, ey, ez, qx, qy, qz);
    Ray R;
    R.d0 = qx - ux;
    R.d1 = qy - uy;
    R.d2 = qz - ds;
    R.p0 = (ux + 1.0f) * 0.5f;
    R.p1 = (uy + 1.0f) * 0.5f;
    R.p2 = (ds + 1.0f) * 0.5f;
    R.sx = (R.d0 >= 0.0f) ? 1 : -1;
    R.sy = (R.d1 >= 0.0f) ? -1 : 1;
    R.cx = xi;
    R.cy = yi;
    march(R);   // initial march: cur_pos, cur_x = x+dx, cur_y = y+dy
    return R;
}

__global__ void k_init(int* ws) { ws[0] = 0; }

// Pass 1: global loop trip count = max over rays of (#steps with pos in NDC box).
// Positions march regardless of mask/hit in the reference, so hits are ignored here.
__global__ __launch_bounds__(256) void k_pass1(const float* proj, const int* xA,
                                               const int* yA, const float* dA,
                                               const float* dsA, int* ws) {
    int r = blockIdx.x * 256 + threadIdx.x;
    Ray R = make_ray(r, proj, xA, yA, dA, dsA);
    int cnt = 0;
    while (cnt < 4096) {
        bool inb = (R.p0 >= 0.0f) && (R.p0 <= 1.0f) &&
                   (R.p1 >= 0.0f) && (R.p1 <= 1.0f) &&
                   (R.p2 > 0.0f) && (R.p2 < 1.0f);
        if (!inb) break;
        march(R);
        cnt++;
    }
    // wave-64 max reduce then one atomic per wave
    for (int o = 32; o; o >>= 1) {
        int v = __shfl_down(cnt, o, 64);
        cnt = cnt > v ? cnt : v;
    }
    if ((threadIdx.x & 63) == 0) atomicMax(ws, cnt);
}

// Pass 2: replay each ray for up to N_total bodies with the exact hit test.
__global__ __launch_bounds__(256) void k_pass2(const float* depth, const float* normal,
                                               const int* idxA, const float* proj,
                                               const int* xA, const int* yA,
                                               const float* dA, const float* dsA,
                                               float* out, const int* ws) {
#pragma clang fp contract(off)
    int r = blockIdx.x * 256 + threadIdx.x;
    int N = ws[0];
    Ray R = make_ray(r, proj, xA, yA, dA, dsA);
    float da = dA[3 * r + 0], db = dA[3 * r + 1], dc = dA[3 * r + 2];
    int idx = idxA[r];
    const float* dep = depth + idx * (HH * WW);
    const float* nrm = normal + idx * (3 * HH * WW);
    int hit = 0, rx = 0, ry = 0;
    float dzv = 0.0f;
    for (int i = 0; i < N; ++i) {
        // pixel-bounds exit is permanent (monotone walk in step direction)
        if (R.cx < 0 || R.cx >= WW || R.cy < 0 || R.cy >= HH) break;
        int off = R.cy * WW + R.cx;
        float z = dep[off];
        float n0 = nrm[off];
        float n1 = nrm[HH * WW + off];
        float n2 = nrm[2 * HH * WW + off];
        float t0 = da * n0;
        float t1 = db * n1;
        float t2 = dc * n2;
        float dot = (t0 + t1) + t2;
        if (R.p2 >= z && dot <= 0.0f) {
            hit = 1; rx = R.cx; ry = R.cy;
            dzv = R.p2 - z;
            break;
        }
        march(R);
    }
    out[2 * r]     = (float)rx;
    out[2 * r + 1] = (float)ry;
    out[2 * BN + r] = hit ? 1.0f : 0.0f;
    out[3 * BN + r] = dzv;
}

extern "C" void kernel_launch(void* const* d_in, const int* in_sizes, int n_in,
                              void* d_out, int out_size, void* d_ws, size_t ws_size,
                              hipStream_t stream) {
    const float* depth = (const float*)d_in[0];
    const float* normal = (const float*)d_in[1];
    const int* indices = (const int*)d_in[2];
    const float* proj = (const float*)d_in[3];
    const int* x = (const int*)d_in[4];
    const int* y = (const int*)d_in[5];
    const float* d = (const float*)d_in[6];
    const float* ds = (const float*)d_in[7];
    float* out = (float*)d_out;
    int* ws = (int*)d_ws;

    k_init<<<1, 1, 0, stream>>>(ws);
    k_pass1<<<BN / 256, 256, 0, stream>>>(proj, x, y, d, ds, ws);
    k_pass2<<<BN / 256, 256, 0, stream>>>(depth, normal, indices, proj, x, y, d, ds, out, ws);
}

// Round 2
// 122.819 us; speedup vs baseline: 1.0876x; 1.0876x over previous
//
#include <hip/hip_runtime.h>
#include <math.h>

// Bit-exact float32 replication of the JAX-CPU reference chain.
// FP contraction off: XLA CPU emits individually-rounded mul/add.
#pragma clang fp contract(off)

#define BN 65536
#define SN 4
#define HH 128
#define WW 128

struct Ray {
    float p0, p1, p2;   // cur_pos
    float d0, d1, d2;   // d_proj (ray_dir)
    int cx, cy, sx, sy;
};

// jnp.linalg.inv(proj) as computed by JAX-CPU (LAPACK sgetf2 + OpenBLAS trsm).
__device__ __forceinline__ void inv4(const float* P, float U[4][4]) {
#pragma clang fp contract(off)
    float a = P[10];
    float b = P[11];
    float ra = 1.0f / a;
    float l32 = P[14] * ra;
    float t = l32 * b;
    float u33 = 0.0f - t;
    float rf0 = 1.0f / P[0];
    float rf1 = 1.0f / P[5];
    float ru  = 1.0f / u33;
#pragma unroll
    for (int i = 0; i < 4; i++)
#pragma unroll
        for (int j = 0; j < 4; j++) U[i][j] = 0.0f;
    U[0][0] = rf0;
    U[1][1] = rf1;
    float x3c2 = (0.0f - l32) * ru;
    float y2c2 = fmaf(0.0f - b, x3c2, 1.0f);
    U[2][2] = y2c2 * ra;
    U[3][2] = x3c2;
    float x3c3 = ru;
    float y2c3 = 0.0f - (b * x3c3);
    U[2][3] = y2c3 * ra;
    U[3][3] = x3c3;
}

// pos4 @ M.T, sequential mul+add (Eigen gemm without FMA), all terms kept.
__device__ __forceinline__ void xform(const float M[4][4], float x, float y, float z,
                                      float& ox, float& oy, float& oz) {
#pragma clang fp contract(off)
    float o[4];
#pragma unroll
    for (int i = 0; i < 4; i++) {
        float acc = x * M[i][0];
        acc = acc + y * M[i][1];
        acc = acc + z * M[i][2];
        acc = acc + M[i][3];
        o[i] = acc;
    }
    ox = o[0] / o[3];
    oy = o[1] / o[3];
    oz = o[2] / o[3];
}

__device__ __forceinline__ void march(Ray& R) {
#pragma clang fp contract(off)
    float nbx = (float)(R.cx + R.sx) / 128.0f;
    float nby = (float)(R.cy + R.sy) / 128.0f;
    float c1 = 1.0f - nby;
    float s0 = (nbx - R.p0) / R.d0;
    float s1 = (c1 - R.p1) / R.d1;
    bool ty = s0 > s1;                 // NaN compare -> false (matches numpy)
    float t = ty ? s1 : s0;
    if (s1 != s1) t = s1;              // jnp.min propagates NaN
    R.p0 = R.p0 + R.d0 * t;
    R.p1 = R.p1 + R.d1 * t;
    R.p2 = R.p2 + R.d2 * t;
    if (ty) R.cy += R.sy; else R.cx += R.sx;
}

__device__ __forceinline__ Ray make_ray(int r, const float* proj, const int* xA,
                                        const int* yA, const float* dA, const float* dsA) {
#pragma clang fp contract(off)
    float P[4][4];
#pragma unroll
    for (int i = 0; i < 16; i++) ((float*)P)[i] = proj[i];
    float U[4][4];
    inv4(proj, U);
    int xi = xA[r], yi = yA[r];
    float t0 = ((float)xi + 0.5f) / 128.0f;
    float t1 = 1.0f - ((float)yi + 0.5f) / 128.0f;
    float ux = t0 * 2.0f - 1.0f;
    float uy = t1 * 2.0f - 1.0f;
    float ds = dsA[r] * 2.0f - 1.0f;
    float vx, vy, vz;
    xform(U, ux, uy, ds, vx, vy, vz);
    float ex = vx + dA[3 * r + 0] * 0.001f;
    float ey = vy + dA[3 * r + 1] * 0.001f;
    float ez = vz + dA[3 * r + 2] * 0.001f;
    float qx, qy, qz;
    xform(P, ex, ey, ez, qx, qy, qz);
    Ray R;
    R.d0 = qx - ux;
    R.d1 = qy - uy;
    R.d2 = qz - ds;
    R.p0 = (ux + 1.0f) * 0.5f;
    R.p1 = (uy + 1.0f) * 0.5f;
    R.p2 = (ds + 1.0f) * 0.5f;
    R.sx = (R.d0 >= 0.0f) ? 1 : -1;
    R.sy = (R.d1 >= 0.0f) ? -1 : 1;
    R.cx = xi;
    R.cy = yi;
    march(R);   // initial march: cur_pos, cur_x = x+dx, cur_y = y+dy
    return R;
}

__global__ void k_init(int* ws) { ws[0] = 0; }

// Merged march: computes B_r (in-box prefix length, for global N = max B_r)
// AND the first-hit record in ONE march per ray, with a 1-state-lag load
// pipeline: loads for state i are issued while state i-1 is tested, so L2
// latency hides under the march arithmetic (divides) of the next step.
// Marching never depends on the hit test (speculative), only the break does.
__global__ __launch_bounds__(256) void k_march(const float* depth, const float* normal,
                                               const int* idxA, const float* proj,
                                               const int* xA, const int* yA,
                                               const float* dA, const float* dsA,
                                               float* out, int* ws) {
#pragma clang fp contract(off)
    int r = blockIdx.x * 256 + threadIdx.x;
    Ray R = make_ray(r, proj, xA, yA, dA, dsA);
    float da = dA[3 * r + 0], db = dA[3 * r + 1], dc = dA[3 * r + 2];
    int idx = idxA[r];
    const float* dep = depth + idx * (HH * WW);
    const float* nrm = normal + idx * (3 * HH * WW);

    int B = 0;                 // in-box prefix length (pass1 semantics)
    bool inbox_run = true;
    bool testing = true;       // still seeking first hit
    bool hit = false;
    int k = 0, rx = 0, ry = 0;
    float dzv = 0.0f;

    // pending-test slot (state i-1)
    bool p_valid = false, p_inpix = false;
    int p_cx = 0, p_cy = 0, p_k = 0;
    float p_p2 = 0.0f;
    float l_z = 0.0f, l_n0 = 0.0f, l_n1 = 0.0f, l_n2 = 0.0f;

    int i = 0;
    while (i < 4096) {
        // box accounting at state i (prefix, matches prior pass1)
        if (inbox_run) {
            bool ib = (R.p0 >= 0.0f) && (R.p0 <= 1.0f) &&
                      (R.p1 >= 0.0f) && (R.p1 <= 1.0f) &&
                      (R.p2 > 0.0f) && (R.p2 < 1.0f);
            if (ib) B = i + 1; else inbox_run = false;
        }
        // consume pending test for state i-1 (loads have had a full body to land)
        if (p_valid) {
            float t0 = da * l_n0;
            float t1 = db * l_n1;
            float t2 = dc * l_n2;
            float dot = (t0 + t1) + t2;
            if (p_inpix && (p_p2 >= l_z) && (dot <= 0.0f)) {
                hit = true; testing = false;
                k = p_k; rx = p_cx; ry = p_cy;
                dzv = p_p2 - l_z;
            }
            p_valid = false;
        }
        bool inpix = (R.cx >= 0) && (R.cx < WW) && (R.cy >= 0) && (R.cy < HH);
        if (!inpix) testing = false;   // pixel exit is permanent (monotone walk)
        if (!testing && !inbox_run) break;
        if (testing) {
            int xs = R.cx < 0 ? 0 : (R.cx > WW - 1 ? WW - 1 : R.cx);
            int ys = R.cy < 0 ? 0 : (R.cy > HH - 1 ? HH - 1 : R.cy);
            int off = ys * WW + xs;
            l_z  = dep[off];
            l_n0 = nrm[off];
            l_n1 = nrm[HH * WW + off];
            l_n2 = nrm[2 * HH * WW + off];
            p_valid = true; p_inpix = inpix;
            p_cx = R.cx; p_cy = R.cy; p_p2 = R.p2; p_k = i;
        }
        march(R);
        i++;
    }
    // drain (only reachable via the i-cap; kept for safety)
    if (p_valid && testing && !hit) {
        float t0 = da * l_n0;
        float t1 = db * l_n1;
        float t2 = dc * l_n2;
        float dot = (t0 + t1) + t2;
        if (p_inpix && (p_p2 >= l_z) && (dot <= 0.0f)) {
            hit = true; k = p_k; rx = p_cx; ry = p_cy; dzv = p_p2 - l_z;
        }
    }

    // pack record into d_out (all values exactly representable in f32)
    int pk = hit ? (rx | (ry << 7) | (1 << 14)) : 0;
    out[2 * r]      = (float)pk;
    out[2 * r + 1]  = (float)k;
    out[3 * BN + r] = dzv;

    // wave-64 max reduce then one atomic per wave: N = max B_r
    for (int o = 32; o; o >>= 1) {
        int v = __shfl_down(B, o, 64);
        B = B > v ? B : v;
    }
    if ((threadIdx.x & 63) == 0) atomicMax(ws, B);
}

// Finalize: apply global trip count N (hit valid iff first-hit index k < N).
__global__ __launch_bounds__(256) void k_final(float* out, const int* ws) {
    int r = blockIdx.x * 256 + threadIdx.x;
    int N = ws[0];
    int pk = (int)out[2 * r];
    int k  = (int)out[2 * r + 1];
    float dzv = out[3 * BN + r];
    bool hit = (pk >> 14) & 1;
    bool ok = hit && (k < N);
    int rx = pk & 127, ry = (pk >> 7) & 127;
    out[2 * r]      = ok ? (float)rx : 0.0f;
    out[2 * r + 1]  = ok ? (float)ry : 0.0f;
    out[2 * BN + r] = ok ? 1.0f : 0.0f;
    out[3 * BN + r] = ok ? dzv : 0.0f;
}

extern "C" void kernel_launch(void* const* d_in, const int* in_sizes, int n_in,
                              void* d_out, int out_size, void* d_ws, size_t ws_size,
                              hipStream_t stream) {
    const float* depth = (const float*)d_in[0];
    const float* normal = (const float*)d_in[1];
    const int* indices = (const int*)d_in[2];
    const float* proj = (const float*)d_in[3];
    const int* x = (const int*)d_in[4];
    const int* y = (const int*)d_in[5];
    const float* d = (const float*)d_in[6];
    const float* ds = (const float*)d_in[7];
    float* out = (float*)d_out;
    int* ws = (int*)d_ws;

    k_init<<<1, 1, 0, stream>>>(ws);
    k_march<<<BN / 256, 256, 0, stream>>>(depth, normal, indices, proj, x, y, d, ds, out, ws);
    k_final<<<BN / 256, 256, 0, stream>>>(out, ws);
}

// Round 3
// 105.348 us; speedup vs baseline: 1.2680x; 1.1658x over previous
//
#include <hip/hip_runtime.h>
#include <math.h>

// Bit-exact float32 replication of the JAX-CPU reference chain.
// FP contraction off: XLA CPU emits individually-rounded mul/add.
#pragma clang fp contract(off)

#define BN 65536
#define SN 4
#define HH 128
#define WW 128

struct Ray {
    float p0, p1, p2;   // cur_pos
    float d0, d1, d2;   // d_proj (ray_dir)
    int cx, cy, sx, sy;
};

// jnp.linalg.inv(proj) as computed by JAX-CPU (LAPACK sgetf2 + OpenBLAS trsm).
__device__ __forceinline__ void inv4(const float* P, float U[4][4]) {
#pragma clang fp contract(off)
    float a = P[10];
    float b = P[11];
    float ra = 1.0f / a;
    float l32 = P[14] * ra;
    float t = l32 * b;
    float u33 = 0.0f - t;
    float rf0 = 1.0f / P[0];
    float rf1 = 1.0f / P[5];
    float ru  = 1.0f / u33;
#pragma unroll
    for (int i = 0; i < 4; i++)
#pragma unroll
        for (int j = 0; j < 4; j++) U[i][j] = 0.0f;
    U[0][0] = rf0;
    U[1][1] = rf1;
    float x3c2 = (0.0f - l32) * ru;
    float y2c2 = fmaf(0.0f - b, x3c2, 1.0f);
    U[2][2] = y2c2 * ra;
    U[3][2] = x3c2;
    float x3c3 = ru;
    float y2c3 = 0.0f - (b * x3c3);
    U[2][3] = y2c3 * ra;
    U[3][3] = x3c3;
}

// pos4 @ M.T, sequential mul+add (Eigen gemm without FMA), all terms kept.
__device__ __forceinline__ void xform(const float M[4][4], float x, float y, float z,
                                      float& ox, float& oy, float& oz) {
#pragma clang fp contract(off)
    float o[4];
#pragma unroll
    for (int i = 0; i < 4; i++) {
        float acc = x * M[i][0];
        acc = acc + y * M[i][1];
        acc = acc + z * M[i][2];
        acc = acc + M[i][3];
        o[i] = acc;
    }
    ox = o[0] / o[3];
    oy = o[1] / o[3];
    oz = o[2] / o[3];
}

__device__ __forceinline__ void march(Ray& R) {
#pragma clang fp contract(off)
    float nbx = (float)(R.cx + R.sx) / 128.0f;
    float nby = (float)(R.cy + R.sy) / 128.0f;
    float c1 = 1.0f - nby;
    float s0 = (nbx - R.p0) / R.d0;
    float s1 = (c1 - R.p1) / R.d1;
    bool ty = s0 > s1;                 // NaN compare -> false (matches numpy)
    float t = ty ? s1 : s0;
    if (s1 != s1) t = s1;              // jnp.min propagates NaN
    R.p0 = R.p0 + R.d0 * t;
    R.p1 = R.p1 + R.d1 * t;
    R.p2 = R.p2 + R.d2 * t;
    if (ty) R.cy += R.sy; else R.cx += R.sx;
}

__device__ __forceinline__ Ray make_ray(int r, const float* proj, const int* xA,
                                        const int* yA, const float* dA, const float* dsA) {
#pragma clang fp contract(off)
    float P[4][4];
#pragma unroll
    for (int i = 0; i < 16; i++) ((float*)P)[i] = proj[i];
    float U[4][4];
    inv4(proj, U);
    int xi = xA[r], yi = yA[r];
    float t0 = ((float)xi + 0.5f) / 128.0f;
    float t1 = 1.0f - ((float)yi + 0.5f) / 128.0f;
    float ux = t0 * 2.0f - 1.0f;
    float uy = t1 * 2.0f - 1.0f;
    float ds = dsA[r] * 2.0f - 1.0f;
    float vx, vy, vz;
    xform(U, ux, uy, ds, vx, vy, vz);
    float ex = vx + dA[3 * r + 0] * 0.001f;
    float ey = vy + dA[3 * r + 1] * 0.001f;
    float ez = vz + dA[3 * r + 2] * 0.001f;
    float qx, qy, qz;
    xform(P, ex, ey, ez, qx, qy, qz);
    Ray R;
    R.d0 = qx - ux;
    R.d1 = qy - uy;
    R.d2 = qz - ds;
    R.p0 = (ux + 1.0f) * 0.5f;
    R.p1 = (uy + 1.0f) * 0.5f;
    R.p2 = (ds + 1.0f) * 0.5f;
    R.sx = (R.d0 >= 0.0f) ? 1 : -1;
    R.sy = (R.d1 >= 0.0f) ? -1 : 1;
    R.cx = xi;
    R.cy = yi;
    march(R);   // initial march: cur_pos, cur_x = x+dx, cur_y = y+dy
    return R;
}

__global__ void k_zero(int* ws) { ws[0] = 0; }

// Build packed per-cell float4 table: (z, n0, n1, n2). 1 MB, L2-resident.
__global__ __launch_bounds__(256) void k_pack(const float* __restrict__ depth,
                                              const float* __restrict__ normal,
                                              float4* __restrict__ tab) {
    int t = blockIdx.x * 256 + threadIdx.x;   // t < SN*HH*WW
    int s = t >> 14;                          // /16384
    int c = t & 16383;
    float4 v;
    v.x = depth[t];
    v.y = normal[s * 3 * HH * WW + c];
    v.z = normal[s * 3 * HH * WW + HH * WW + c];
    v.w = normal[s * 3 * HH * WW + 2 * HH * WW + c];
    tab[t] = v;
}

// Merged march, 2-deep load pipeline (two static slots, manual unroll so all
// slot accesses are compile-time-indexed), branch-light body, wave-vote break.
// State numbering matches R2 (verified): state i is R before the i-th march;
// make_ray already performed the initial march. B = in-box prefix length.
template <bool PACKED>
__global__ __launch_bounds__(256) void k_march(const float* __restrict__ depth,
                                               const float* __restrict__ normal,
                                               const float4* __restrict__ tab,
                                               const int* idxA, const float* proj,
                                               const int* xA, const int* yA,
                                               const float* dA, const float* dsA,
                                               float* out, int* ws) {
#pragma clang fp contract(off)
    int r = blockIdx.x * 256 + threadIdx.x;
    Ray R = make_ray(r, proj, xA, yA, dA, dsA);
    float da = dA[3 * r + 0], db = dA[3 * r + 1], dc = dA[3 * r + 2];
    int idx = idxA[r];
    const float* dep = depth + idx * (HH * WW);
    const float* nrm = normal + idx * (3 * HH * WW);
    const float4* ptab = tab + idx * (HH * WW);

    int B = 0;
    bool inbox_run = true;   // still extending the in-box prefix
    bool issuing = true;     // still generating hit-test states
    bool hit = false;
    int k = 0, rx = 0, ry = 0;
    float dzv = 0.0f;

    // two pipeline slots (A: even states, B: odd states)
    bool vA = false, ipA = false; int kA = 0, cxA = 0, cyA = 0; float pA = 0.0f;
    float zA = 0.0f, n0A = 0.0f, n1A = 0.0f, n2A = 0.0f;
    bool vB = false, ipB = false; int kB = 0, cxB = 0, cyB = 0; float pB = 0.0f;
    float zB = 0.0f, n0B = 0.0f, n1B = 0.0f, n2B = 0.0f;

#define HALF(vS, ipS, kS, cxS, cyS, pS, zS, n0S, n1S, n2S, I)                    \
    {                                                                            \
        /* consume slot (state I-2): first-hit in state order */                 \
        if (vS) {                                                                \
            float t0 = da * n0S;                                                 \
            float t1 = db * n1S;                                                 \
            float t2 = dc * n2S;                                                 \
            float dotv = (t0 + t1) + t2;                                         \
            bool hc = ipS && (pS >= zS) && (dotv <= 0.0f) && !hit;               \
            if (hc) { hit = true; k = kS; rx = cxS; ry = cyS; dzv = pS - zS; }   \
            vS = false;                                                          \
        }                                                                        \
        /* box accounting for state I */                                         \
        if (inbox_run) {                                                         \
            bool ib = (R.p0 >= 0.0f) && (R.p0 <= 1.0f) &&                        \
                      (R.p1 >= 0.0f) && (R.p1 <= 1.0f) &&                        \
                      (R.p2 > 0.0f) && (R.p2 < 1.0f);                            \
            if (ib) B = (I) + 1; else inbox_run = false;                         \
        }                                                                        \
        /* issue state I into slot (unconditional clamped load) */               \
        {                                                                        \
            bool inpix = (R.cx >= 0) && (R.cx < WW) && (R.cy >= 0) && (R.cy < HH); \
            issuing = issuing && inpix && !hit;                                  \
            int xs = R.cx < 0 ? 0 : (R.cx > WW - 1 ? WW - 1 : R.cx);             \
            int ys = R.cy < 0 ? 0 : (R.cy > HH - 1 ? HH - 1 : R.cy);             \
            int off = ys * WW + xs;                                              \
            if (PACKED) {                                                        \
                float4 v = ptab[off];                                            \
                zS = v.x; n0S = v.y; n1S = v.z; n2S = v.w;                       \
            } else {                                                             \
                zS = dep[off];                                                   \
                n0S = nrm[off];                                                  \
                n1S = nrm[HH * WW + off];                                        \
                n2S = nrm[2 * HH * WW + off];                                    \
            }                                                                    \
            vS = issuing; ipS = inpix;                                           \
            kS = (I); cxS = R.cx; cyS = R.cy; pS = R.p2;                         \
        }                                                                        \
        march(R);                                                                \
    }

    int i = 0;
    while (i < 4096) {
        HALF(vA, ipA, kA, cxA, cyA, pA, zA, n0A, n1A, n2A, i)
        i++;
        HALF(vB, ipB, kB, cxB, cyB, pB, zB, n0B, n1B, n2B, i)
        i++;
        if (!__any(inbox_run || issuing || vA || vB)) break;
    }
#undef HALF

    // pack record into d_out (all values exactly representable in f32)
    int pk = hit ? (rx | (ry << 7) | (1 << 14)) : 0;
    out[2 * r]      = (float)pk;
    out[2 * r + 1]  = (float)k;
    out[3 * BN + r] = dzv;

    // wave-64 max reduce then one atomic per wave: N = max B_r
    for (int o = 32; o; o >>= 1) {
        int v = __shfl_down(B, o, 64);
        B = B > v ? B : v;
    }
    if ((threadIdx.x & 63) == 0) atomicMax(ws, B);
}

// Finalize: hit valid iff first-hit state index k < N (global trip count).
__global__ __launch_bounds__(256) void k_final(float* out, const int* ws) {
    int r = blockIdx.x * 256 + threadIdx.x;
    int N = ws[0];
    int pk = (int)out[2 * r];
    int k  = (int)out[2 * r + 1];
    float dzv = out[3 * BN + r];
    bool hit = (pk >> 14) & 1;
    bool ok = hit && (k < N);
    int rx = pk & 127, ry = (pk >> 7) & 127;
    out[2 * r]      = ok ? (float)rx : 0.0f;
    out[2 * r + 1]  = ok ? (float)ry : 0.0f;
    out[2 * BN + r] = ok ? 1.0f : 0.0f;
    out[3 * BN + r] = ok ? dzv : 0.0f;
}

extern "C" void kernel_launch(void* const* d_in, const int* in_sizes, int n_in,
                              void* d_out, int out_size, void* d_ws, size_t ws_size,
                              hipStream_t stream) {
    const float* depth = (const float*)d_in[0];
    const float* normal = (const float*)d_in[1];
    const int* indices = (const int*)d_in[2];
    const float* proj = (const float*)d_in[3];
    const int* x = (const int*)d_in[4];
    const int* y = (const int*)d_in[5];
    const float* d = (const float*)d_in[6];
    const float* ds = (const float*)d_in[7];
    float* out = (float*)d_out;
    int* ws = (int*)d_ws;

    const size_t tab_off = 64;  // bytes; 16B-aligned
    const size_t need = tab_off + (size_t)SN * HH * WW * 16;
    float4* tab = (float4*)((char*)d_ws + tab_off);

    k_zero<<<1, 1, 0, stream>>>(ws);
    if (ws_size >= need) {   // host-uniform: graph-capture safe
        k_pack<<<(SN * HH * WW) / 256, 256, 0, stream>>>(depth, normal, tab);
        k_march<true><<<BN / 256, 256, 0, stream>>>(depth, normal, tab, indices,
                                                    proj, x, y, d, ds, out, ws);
    } else {
        k_march<false><<<BN / 256, 256, 0, stream>>>(depth, normal, tab, indices,
                                                     proj, x, y, d, ds, out, ws);
    }
    k_final<<<BN / 256, 256, 0, stream>>>(out, ws);
}